// Round 1
// baseline (2833.083 us; speedup 1.0000x reference)
//
#include <hip/hip_runtime.h>
#include <hip/hip_bf16.h>

// HMM batched log-forward, B=128, T=8192, S=65 (state 0 = bookend), V=1024.
//
// Math: scaled forward algorithm in linear f32 domain.
//   alpha <- (P^T alpha) .* e_t, rescale by wave-sum every 4 steps,
//   accumulate log(scale) in double. State 0 is dead after init because
//   column 0 of trans is softmaxed from -99 (exp ~ 1e-45): handled exactly
//   at init (arow0) and termination (log-domain logsumexp with tcol).
//
// Mapping: 1 wave per batch (128 blocks x 64 threads). Lane j = state j+1.
// exp(trans) columns in 64 VGPRs/lane; alpha broadcast via v_readlane
// (constant lane index, fully unrolled) into v_fma_f32 SGPR operand.
// Emissions pre-exp'd + transposed (emitT[v][j], 256KB, L2-resident) ->
// one coalesced 256B load per step, pipelined 2 steps ahead via obs in LDS.

#define HMM_B 128
#define HMM_T 8192
#define HMM_S 65
#define HMM_V 1024
#define NS 64  // live states (1..64)

// d_ws float layout:
//   emitT  [0, 65536)        : emitT[v*64 + j] = exp(log_emit[(j+1)*V + v])
//   ET     [65536, 69632)    : ET[i*64 + j]    = exp(log_trans[(i+1)*65 + (j+1)])
//   arow0  [69632, 69696)    : sum_i exp(log_pi[i]) * exp(log_trans[i*65 + (j+1)])
//   tcol   [69696, 69760)    : log_trans[(j+1)*65 + 0]   (kept in log domain)
#define WS_EMITT 0
#define WS_ET    65536
#define WS_AROW0 69632
#define WS_TCOL  69696

__global__ __launch_bounds__(256) void prep_emit(const float* __restrict__ log_emit,
                                                 float* __restrict__ emitT) {
    int idx = blockIdx.x * 256 + threadIdx.x;   // 0 .. 65535
    int v = idx >> 6;
    int j = idx & 63;
    emitT[idx] = expf(log_emit[(j + 1) * HMM_V + v]);
}

__global__ __launch_bounds__(64) void prep_small(const float* __restrict__ log_trans,
                                                 const float* __restrict__ log_pi,
                                                 float* __restrict__ ws) {
    int j = threadIdx.x;  // 0..63 -> state j+1
    float* ET    = ws + WS_ET;
    float* arow0 = ws + WS_AROW0;
    float* tcol  = ws + WS_TCOL;
    for (int i = 0; i < NS; ++i)
        ET[i * 64 + j] = expf(log_trans[(i + 1) * HMM_S + (j + 1)]);
    float s = 0.f;
    for (int i = 0; i < HMM_S; ++i)
        s += expf(log_pi[i]) * expf(log_trans[i * HMM_S + (j + 1)]);
    arow0[j] = s;
    tcol[j] = log_trans[(j + 1) * HMM_S + 0];
}

__global__ __launch_bounds__(64) void hmm_fwd(const int* __restrict__ obvs,
                                              const float* __restrict__ ws,
                                              float* __restrict__ out) {
    __shared__ int obs_s[HMM_T];  // 32 KB
    const int b = blockIdx.x;
    const int lane = threadIdx.x;
    const float* emitT = ws + WS_EMITT;
    const float* ET    = ws + WS_ET;
    const float* arow0 = ws + WS_AROW0;
    const float* tcol  = ws + WS_TCOL;

    // stage this batch's obs sequence into LDS (coalesced)
    const int* obs = obvs + b * HMM_T;
    for (int k = lane; k < HMM_T; k += 64) obs_s[k] = obs[k];

    // transition columns into registers: Pc[i] = P[state i+1][state lane+1]
    float Pc[NS];
#pragma unroll
    for (int i = 0; i < NS; ++i) Pc[i] = ET[i * 64 + lane];

    __syncthreads();

    // ---- t = 0 (peeled: init row covers state 0 exactly) ----
    int o0 = obs_s[0];
    float alpha = arow0[lane] * emitT[o0 * 64 + lane];
    double logscale = 0.0;

    // software pipeline: e_cur = emission[t]; on1 = obs[t+1]; on2 = obs[t+2]
    int on1 = obs_s[1];
    float e_cur = emitT[on1 * 64 + lane];  // emission for t=1
    on1 = obs_s[2];
    int on2 = obs_s[3];

    for (int t = 1; t < HMM_T; ++t) {
        // issue next emission load (for t+1) and obs read (for t+3)
        float e_next = emitT[on1 * 64 + lane];
        int tnn = t + 3;
        int on_new = obs_s[tnn < HMM_T - 1 ? tnn : HMM_T - 1];

        // alpha_new[j] = sum_i alpha[i] * P[i][j], 4 independent chains
        float acc0 = 0.f, acc1 = 0.f, acc2 = 0.f, acc3 = 0.f;
#pragma unroll
        for (int i = 0; i < NS; i += 4) {
            acc0 = fmaf(__int_as_float(__builtin_amdgcn_readlane(__float_as_int(alpha), i + 0)), Pc[i + 0], acc0);
            acc1 = fmaf(__int_as_float(__builtin_amdgcn_readlane(__float_as_int(alpha), i + 1)), Pc[i + 1], acc1);
            acc2 = fmaf(__int_as_float(__builtin_amdgcn_readlane(__float_as_int(alpha), i + 2)), Pc[i + 2], acc2);
            acc3 = fmaf(__int_as_float(__builtin_amdgcn_readlane(__float_as_int(alpha), i + 3)), Pc[i + 3], acc3);
        }
        alpha = ((acc0 + acc1) + (acc2 + acc3)) * e_cur;

        // periodic rescale: keeps alpha in f32 range (>= e^-44 between rescales)
        if ((t & 3) == 0) {
            float s = alpha;
#pragma unroll
            for (int d = 1; d < 64; d <<= 1) s += __shfl_xor(s, d);
            logscale += (double)__logf(s);
            alpha *= (1.0f / s);
        }

        e_cur = e_next;
        on1 = on2;
        on2 = on_new;
    }

    // ---- termination: logsumexp_j( log(alpha_j) + log_trans[j][0] ) + logscale
    float v = __logf(alpha) + tcol[lane];   // alpha==0 -> -inf -> exp() = 0, safe
    float m = v;
#pragma unroll
    for (int d = 1; d < 64; d <<= 1) m = fmaxf(m, __shfl_xor(m, d));
    float s = __expf(v - m);
#pragma unroll
    for (int d = 1; d < 64; d <<= 1) s += __shfl_xor(s, d);
    if (lane == 0)
        out[b] = (float)(logscale + (double)m + (double)__logf(s));
}

extern "C" void kernel_launch(void* const* d_in, const int* in_sizes, int n_in,
                              void* d_out, int out_size, void* d_ws, size_t ws_size,
                              hipStream_t stream) {
    const float* log_trans = (const float*)d_in[0];  // 65*65
    const float* log_emit  = (const float*)d_in[1];  // 65*1024
    const float* log_pi    = (const float*)d_in[2];  // 65
    const int*   obvs      = (const int*)d_in[3];    // 128*8192
    float* ws  = (float*)d_ws;
    float* out = (float*)d_out;

    prep_emit<<<256, 256, 0, stream>>>(log_emit, ws + WS_EMITT);
    prep_small<<<1, 64, 0, stream>>>(log_trans, log_pi, ws);
    hmm_fwd<<<HMM_B, 64, 0, stream>>>(obvs, ws, out);
}

// Round 2
// 1996.519 us; speedup vs baseline: 1.4190x; 1.4190x over previous
//
#include <hip/hip_runtime.h>
#include <hip/hip_bf16.h>

// HMM batched forward, B=128, T=8192, S=65 (state 0 = bookend dead after init), V=1024.
//
// R2 design: serial chain is the only cost (1 wave per batch, GPU 98.5% idle).
// (1) Two-step fusion: M_v = ET^T? no -- M_v[i][m] = sum_j ET[i][j] e_v[j] ET[j][m],
//     per-v scaled to max~2^11, f16, 8KB/matrix, 8MB table (device global, L2/L3 resident).
//     4096 serial "apps" instead of 8192 steps. App 0 = plain 1-step table (P1).
// (2) 8x8 lane decomposition, lane = 8h+l. Parity alternation: even apps use
//     (iblk,jblk)=(l,h) and reduce over l via DPP (quad_perm xor1/xor2 + row_half_mirror);
//     odd apps use (h,l) and reduce over h via shfl_xor 8/16/32. Output block index of
//     one parity == input block index of the next: no transpose, no readlane.
// (3) f16 v_dot2_f32_f16 for the 64 MACs/lane (32 dot2), f32 accumulate.
// (4) Rescale every app (sum-normalize, logscale += log s + slog_v); keeps alpha in
//     f16-representable range even worst-case.

#define HMM_B 128
#define HMM_T 8192
#define HMM_S 65
#define HMM_V 1024
#define LN2F 0.69314718055994531f

typedef __fp16 v2h __attribute__((ext_vector_type(2)));

// ---------------- device-global scratch (avoids ws_size uncertainty) ----------------
__device__ __attribute__((aligned(16))) __fp16 gMtab[HMM_V * 4096]; // blocked 2-step tables
__device__ __attribute__((aligned(16))) __fp16 gP1[4096];           // blocked 1-step table
__device__ __attribute__((aligned(16))) float  gEmitT[HMM_V * 64];  // exp emissions [v][j]
__device__ float gSlog[HMM_V];   // log2-scale correction per v (in nats)
__device__ float gET[64 * 64];   // exp transitions, live states [i][j]
__device__ __attribute__((aligned(16))) float gArow0[64];
__device__ __attribute__((aligned(16))) float gTcs[64];  // exp(tcol - tcmax)
__device__ float gTcmax;

// blocked f16 table layout: entry (i,m) of a 64x64 matrix ->
//   block (ib=i>>3, jb=m>>3) of 64 f16, within: pair-major for dot2:
//   ((i&7)>>1)*16 + (m&7)*2 + (i&1)
__host__ __device__ __forceinline__ int blk_idx(int i, int m) {
    return (((i >> 3) * 8 + (m >> 3)) * 64) + (((i & 7) >> 1) * 16) + ((m & 7) * 2) + (i & 1);
}

// ---------------- helpers ----------------
__device__ __forceinline__ float fdot2_(v2h a, v2h b, float c) {
#if __has_builtin(__builtin_amdgcn_fdot2)
    return __builtin_amdgcn_fdot2(a, b, c, false);
#else
    return c + (float)a.x * (float)b.x + (float)a.y * (float)b.y;
#endif
}

template <int CTRL>
__device__ __forceinline__ float dpp_add(float x) {
    // x + dpp_permuted(x); CTRL: 0xB1=quad_perm[1,0,3,2] (xor1),
    // 0x4E=quad_perm[2,3,0,1] (xor2), 0x141=row_half_mirror (completes 8-lane allreduce)
    return x + __int_as_float(__builtin_amdgcn_update_dpp(
                   0, __float_as_int(x), CTRL, 0xF, 0xF, true));
}

__device__ __forceinline__ float fast_rcp(float x) {
#if __has_builtin(__builtin_amdgcn_rcpf)
    return __builtin_amdgcn_rcpf(x);
#else
    return 1.0f / x;
#endif
}

__device__ __forceinline__ v2h as_v2h(int x) { return __builtin_bit_cast(v2h, x); }

#define RED_LOW_ALL(r)                      \
    _Pragma("unroll")                       \
    for (int m_ = 0; m_ < 8; ++m_) {        \
        r[m_] = dpp_add<0xB1>(r[m_]);       \
        r[m_] = dpp_add<0x4E>(r[m_]);       \
        r[m_] = dpp_add<0x141>(r[m_]);      \
    }

#define RED_HIGH_ALL(r)                     \
    _Pragma("unroll")                       \
    for (int m_ = 0; m_ < 8; ++m_) {        \
        r[m_] += __shfl_xor(r[m_], 8);      \
        r[m_] += __shfl_xor(r[m_], 16);     \
        r[m_] += __shfl_xor(r[m_], 32);     \
    }

// compute one application with table TB (int[32] regs), emission E0/E1 (float4),
// scale-log SLOG. MAIN_LOW: reduce matvec over low lane bits (even apps) else high.
#define COMPUTE_APP(TB, E0, E1, SLOG, MAIN_LOW)                                     \
    {                                                                               \
        v2h ap0 = __builtin_amdgcn_cvt_pkrtz(ab[0], ab[1]);                         \
        v2h ap1 = __builtin_amdgcn_cvt_pkrtz(ab[2], ab[3]);                         \
        v2h ap2 = __builtin_amdgcn_cvt_pkrtz(ab[4], ab[5]);                         \
        v2h ap3 = __builtin_amdgcn_cvt_pkrtz(ab[6], ab[7]);                         \
        float r[8];                                                                 \
        _Pragma("unroll")                                                           \
        for (int m = 0; m < 8; ++m) {                                               \
            float acc = fdot2_(ap0, as_v2h(TB[m]), 0.0f);                           \
            acc = fdot2_(ap1, as_v2h(TB[8 + m]), acc);                              \
            acc = fdot2_(ap2, as_v2h(TB[16 + m]), acc);                             \
            acc = fdot2_(ap3, as_v2h(TB[24 + m]), acc);                             \
            r[m] = acc;                                                             \
        }                                                                           \
        if (MAIN_LOW) { RED_LOW_ALL(r) } else { RED_HIGH_ALL(r) }                   \
        r[0] *= E0.x; r[1] *= E0.y; r[2] *= E0.z; r[3] *= E0.w;                     \
        r[4] *= E1.x; r[5] *= E1.y; r[6] *= E1.z; r[7] *= E1.w;                     \
        float s_ = ((r[0] + r[1]) + (r[2] + r[3])) + ((r[4] + r[5]) + (r[6] + r[7])); \
        if (MAIN_LOW) {                                                             \
            s_ += __shfl_xor(s_, 8); s_ += __shfl_xor(s_, 16); s_ += __shfl_xor(s_, 32); \
        } else {                                                                    \
            s_ = dpp_add<0xB1>(s_); s_ = dpp_add<0x4E>(s_); s_ = dpp_add<0x141>(s_); \
        }                                                                           \
        float inv_ = fast_rcp(s_);                                                  \
        logscale += SLOG + __logf(s_);                                              \
        _Pragma("unroll")                                                           \
        for (int m = 0; m < 8; ++m) ab[m] = r[m] * inv_;                            \
    }

// ---------------- prep kernels ----------------
__global__ __launch_bounds__(256) void prep_emit(const float* __restrict__ log_emit) {
    int idx = blockIdx.x * 256 + threadIdx.x;  // 0..65535
    int v = idx >> 6;
    int j = idx & 63;
    gEmitT[idx] = expf(log_emit[(j + 1) * HMM_V + v]);
}

__global__ __launch_bounds__(64) void prep_small(const float* __restrict__ log_trans,
                                                 const float* __restrict__ log_pi) {
    int j = threadIdx.x;  // live state j+1
    for (int i = 0; i < 64; ++i)
        gET[i * 64 + j] = expf(log_trans[(i + 1) * HMM_S + (j + 1)]);
    float s = 0.f;
    for (int i = 0; i < HMM_S; ++i)
        s += expf(log_pi[i]) * expf(log_trans[i * HMM_S + (j + 1)]);
    gArow0[j] = s;
    float tc = log_trans[(j + 1) * HMM_S + 0];
    float mx = tc;
    for (int d = 1; d < 64; d <<= 1) mx = fmaxf(mx, __shfl_xor(mx, d));
    gTcs[j] = expf(tc - mx);
    if (j == 0) gTcmax = mx;
    // blocked 1-step table: P1[i][m] = ET[i][m] (this thread owns column j == m)
    for (int i = 0; i < 64; ++i)
        gP1[blk_idx(i, j)] = (__fp16)gET[i * 64 + j];
}

__global__ __launch_bounds__(64) void prep_table() {
    __shared__ float ETs[64 * 64];  // [i][j], broadcast reads
    __shared__ float ETp[64 * 66];  // [j][m], padded (bank-conflict-free per-thread m)
    __shared__ float ev[64];
    const int m = threadIdx.x;
    const int v = blockIdx.x;
    for (int i = 0; i < 64; ++i) ETs[i * 64 + m] = gET[i * 64 + m];
    for (int j = 0; j < 64; ++j) ETp[j * 66 + m] = gET[j * 64 + m];
    ev[m] = gEmitT[v * 64 + m];
    __syncthreads();
    float acc[64];
#pragma unroll
    for (int i = 0; i < 64; ++i) acc[i] = 0.f;
    for (int j = 0; j < 64; ++j) {
        float w = ev[j] * ETp[j * 66 + m];  // e_v[j] * ET[j][m]
#pragma unroll
        for (int i = 0; i < 64; ++i) acc[i] = fmaf(ETs[i * 64 + j], w, acc[i]);
    }
    float mx = acc[0];
#pragma unroll
    for (int i = 1; i < 64; ++i) mx = fmaxf(mx, acc[i]);
    for (int d = 1; d < 64; d <<= 1) mx = fmaxf(mx, __shfl_xor(mx, d));
    int e;
    (void)frexpf(mx, &e);                 // mx = f * 2^e, f in [0.5,1)
    float sc = exp2f((float)(11 - e));    // scaled max in [1024, 2048): f16-safe headroom
    if (m == 0) gSlog[v] = (float)(e - 11) * LN2F;
    __fp16* outp = gMtab + v * 4096;
    for (int i = 0; i < 64; ++i) outp[blk_idx(i, m)] = (__fp16)(acc[i] * sc);
}

// ---------------- main serial-scan kernel: 1 wave per batch ----------------
__global__ __launch_bounds__(64) void hmm_fwd(const int* __restrict__ obvs,
                                              float* __restrict__ out) {
    __shared__ __attribute__((aligned(16))) int obs_s[2 * 4100];  // padded pairs
    __shared__ float a0lds[64];
    const int b = blockIdx.x;
    const int lane = threadIdx.x;
    const int h = lane >> 3, l = lane & 7;

    const int* obs = obvs + b * HMM_T;
    for (int k = lane; k < HMM_T; k += 64) obs_s[k] = obs[k];
    if (lane < 8) obs_s[HMM_T + lane] = 0;  // pad for tail prefetch

    const int blkE = (l * 8 + h) * 8;  // int4 offset of lane's block, even apps
    const int blkO = (h * 8 + l) * 8;  // odd apps
    const int ebE = h * 2;             // float4 offset of lane's emission chunk, even
    const int ebO = l * 2;             // odd

    const int4* Mtab4 = (const int4*)gMtab;  // 512 int4 per v
    const int4* P14 = (const int4*)gP1;
    const float4* Em4 = (const float4*)gEmitT;  // 16 float4 per v
    const int2* obs2 = (const int2*)obs_s;      // obs2[a] = (obs[2a], obs[2a+1])

    // ---- init t=0 (exact: includes bookend state) ----
    int o0 = obs_s[0];
    float a0 = gArow0[lane] * gEmitT[o0 * 64 + lane];
    a0lds[lane] = a0;  // same-wave LDS handoff to blocked layout
    float ab[8];
#pragma unroll
    for (int k = 0; k < 8; ++k) ab[k] = a0lds[l * 8 + k];  // invariant A: alpha[8l+k]

    float logscale = 0.f;

    // double-buffered state: A = even-app buffers, B = odd-app buffers
    int tbA[32], tbB[32];
    float4 ebA0, ebA1, ebB0, ebB1;
    float slogA, slogB;
    int2 obpA, obpB;

    // prologue: prefetch app 0 (1-step P1 table, emission obs[1])
#pragma unroll
    for (int i = 0; i < 8; ++i) {
        int4 t = P14[blkE + i];
        tbA[4 * i + 0] = t.x; tbA[4 * i + 1] = t.y;
        tbA[4 * i + 2] = t.z; tbA[4 * i + 3] = t.w;
    }
    {
        int v2 = obs_s[1];
        ebA0 = Em4[v2 * 16 + ebE];
        ebA1 = Em4[v2 * 16 + ebE + 1];
    }
    slogA = 0.f;
    obpB = obs2[1];  // pair for app 1
    obpA = obs2[2];  // pair for app 2 (body 0 overwrites identically)

    for (int k = 0; k < 2048; ++k) {
        const int a = 2 * k;
        // ---- even body: compute app a (buffers A), prefetch odd app a+1 into B ----
        {
            int v1n = obpB.x, v2n = obpB.y;
            const int4* tbase = Mtab4 + v1n * 512 + blkO;
#pragma unroll
            for (int i = 0; i < 8; ++i) {
                int4 t = tbase[i];
                tbB[4 * i + 0] = t.x; tbB[4 * i + 1] = t.y;
                tbB[4 * i + 2] = t.z; tbB[4 * i + 3] = t.w;
            }
            ebB0 = Em4[v2n * 16 + ebO];
            ebB1 = Em4[v2n * 16 + ebO + 1];
            slogB = gSlog[v1n];
            obpA = obs2[a + 2];
            COMPUTE_APP(tbA, ebA0, ebA1, slogA, true)
        }
        // ---- odd body: compute app a+1 (buffers B), prefetch even app a+2 into A ----
        {
            int v1n = obpA.x, v2n = obpA.y;
            const int4* tbase = Mtab4 + v1n * 512 + blkE;
#pragma unroll
            for (int i = 0; i < 8; ++i) {
                int4 t = tbase[i];
                tbA[4 * i + 0] = t.x; tbA[4 * i + 1] = t.y;
                tbA[4 * i + 2] = t.z; tbA[4 * i + 3] = t.w;
            }
            ebA0 = Em4[v2n * 16 + ebE];
            ebA1 = Em4[v2n * 16 + ebE + 1];
            slogA = gSlog[v1n];
            obpB = obs2[a + 3];
            COMPUTE_APP(tbB, ebB0, ebB1, slogB, false)
        }
    }

    // ---- termination: last app odd -> invariant A: ab[m] = alpha[8l+m] ----
    float t = 0.f;
#pragma unroll
    for (int m = 0; m < 8; ++m) t += ab[m] * gTcs[l * 8 + m];
    t = dpp_add<0xB1>(t);
    t = dpp_add<0x4E>(t);
    t = dpp_add<0x141>(t);  // sum over l-blocks
    if (lane == 0) out[b] = logscale + gTcmax + __logf(t);
}

// ---------------- launch ----------------
extern "C" void kernel_launch(void* const* d_in, const int* in_sizes, int n_in,
                              void* d_out, int out_size, void* d_ws, size_t ws_size,
                              hipStream_t stream) {
    const float* log_trans = (const float*)d_in[0];  // 65*65
    const float* log_emit  = (const float*)d_in[1];  // 65*1024
    const float* log_pi    = (const float*)d_in[2];  // 65
    const int*   obvs      = (const int*)d_in[3];    // 128*8192
    float* out = (float*)d_out;

    prep_emit<<<256, 256, 0, stream>>>(log_emit);
    prep_small<<<1, 64, 0, stream>>>(log_trans, log_pi);
    prep_table<<<1024, 64, 0, stream>>>();
    hmm_fwd<<<HMM_B, 64, 0, stream>>>(obvs, out);
}

// Round 3
// 1626.876 us; speedup vs baseline: 1.7414x; 1.2272x over previous
//
#include <hip/hip_runtime.h>
#include <hip/hip_bf16.h>

// HMM batched forward, B=128, T=8192, S=65 (state 0 = bookend dead after init), V=1024.
//
// R3 design: serial chain + deep prefetch (R2 post-mortem: 90% of wave time was
// exposed VMEM latency on the 8KB/app table loads -> depth-4 pipeline).
// (1) Two-step fusion: M_v[i][m] = sum_j ET[i][j] e_v[j] ET[j][m], per-v scaled to
//     max~2^11, f16, 8KB/matrix, 8MB table. 4096 serial apps. App 0 = 1-step P1.
// (2) 8x8 lane decomposition, lane = 8h+l, parity alternation (even apps reduce over
//     low lane bits via DPP, odd over high via shfl_xor) -> no transpose, no readlane.
// (3) f16 v_dot2_f32_f16, f32 accumulate.
// (4) Power-of-2 renorm each app: e = frexp_exp(sum), ab *= 2^-e, eacc += e (int),
//     slogsum += slog_v (float). No transcendental on the per-app chain.
// (5) Depth-4 ring: prefetch for app a+3 issued while computing app a (~3 apps
//     ~= 750-900 cyc of latency cover vs ~900 cyc HBM-miss latency).

#define HMM_B 128
#define HMM_T 8192
#define HMM_S 65
#define HMM_V 1024
#define LN2 0.6931471805599453

typedef __fp16 v2h __attribute__((ext_vector_type(2)));

// ---------------- device-global scratch ----------------
__device__ __attribute__((aligned(16))) __fp16 gMtab[HMM_V * 4096]; // blocked 2-step tables
__device__ __attribute__((aligned(16))) __fp16 gP1[4096];           // blocked 1-step table
__device__ __attribute__((aligned(16))) float  gEmitT[HMM_V * 64];  // exp emissions [v][j]
__device__ float gSlog[HMM_V];   // scale correction per v (nats)
__device__ float gET[64 * 64];   // exp transitions, live states [i][j]
__device__ __attribute__((aligned(16))) float gArow0[64];
__device__ __attribute__((aligned(16))) float gTcs[64];  // exp(tcol - tcmax)
__device__ float gTcmax;

// blocked f16 table layout: entry (i,m) -> block (i>>3, m>>3) of 64 f16,
// within-block pair-major for dot2: ((i&7)>>1)*16 + (m&7)*2 + (i&1)
__host__ __device__ __forceinline__ int blk_idx(int i, int m) {
    return (((i >> 3) * 8 + (m >> 3)) * 64) + (((i & 7) >> 1) * 16) + ((m & 7) * 2) + (i & 1);
}

// ---------------- helpers ----------------
__device__ __forceinline__ float fdot2_(v2h a, v2h b, float c) {
#if __has_builtin(__builtin_amdgcn_fdot2)
    return __builtin_amdgcn_fdot2(a, b, c, false);
#else
    return c + (float)a.x * (float)b.x + (float)a.y * (float)b.y;
#endif
}

template <int CTRL>
__device__ __forceinline__ float dpp_add(float x) {
    // x + dpp(x); 0xB1=quad_perm xor1, 0x4E=quad_perm xor2, 0x141=row_half_mirror
    return x + __int_as_float(__builtin_amdgcn_update_dpp(
                   0, __float_as_int(x), CTRL, 0xF, 0xF, true));
}

__device__ __forceinline__ v2h as_v2h(int x) { return __builtin_bit_cast(v2h, x); }

#define RED_LOW_ALL(r)                      \
    _Pragma("unroll")                       \
    for (int m_ = 0; m_ < 8; ++m_) {        \
        r[m_] = dpp_add<0xB1>(r[m_]);       \
        r[m_] = dpp_add<0x4E>(r[m_]);       \
        r[m_] = dpp_add<0x141>(r[m_]);      \
    }

#define RED_HIGH_ALL(r)                     \
    _Pragma("unroll")                       \
    for (int m_ = 0; m_ < 8; ++m_) {        \
        r[m_] += __shfl_xor(r[m_], 8);      \
        r[m_] += __shfl_xor(r[m_], 16);     \
        r[m_] += __shfl_xor(r[m_], 32);     \
    }

// one application: table TB (int[32]), emissions E0/E1 (float4), scale-log SLOG.
// MAIN_LOW: reduce matvec over low lane bits (even apps) else high (odd apps).
#define COMPUTE_APP(TB, E0, E1, SLOG, MAIN_LOW)                                     \
    {                                                                               \
        v2h ap0 = __builtin_amdgcn_cvt_pkrtz(ab[0], ab[1]);                         \
        v2h ap1 = __builtin_amdgcn_cvt_pkrtz(ab[2], ab[3]);                         \
        v2h ap2 = __builtin_amdgcn_cvt_pkrtz(ab[4], ab[5]);                         \
        v2h ap3 = __builtin_amdgcn_cvt_pkrtz(ab[6], ab[7]);                         \
        float r[8];                                                                 \
        _Pragma("unroll")                                                           \
        for (int m = 0; m < 8; ++m) {                                               \
            float acc = fdot2_(ap0, as_v2h(TB[m]), 0.0f);                           \
            acc = fdot2_(ap1, as_v2h(TB[8 + m]), acc);                              \
            acc = fdot2_(ap2, as_v2h(TB[16 + m]), acc);                             \
            acc = fdot2_(ap3, as_v2h(TB[24 + m]), acc);                             \
            r[m] = acc;                                                             \
        }                                                                           \
        if (MAIN_LOW) { RED_LOW_ALL(r) } else { RED_HIGH_ALL(r) }                   \
        r[0] *= E0.x; r[1] *= E0.y; r[2] *= E0.z; r[3] *= E0.w;                     \
        r[4] *= E1.x; r[5] *= E1.y; r[6] *= E1.z; r[7] *= E1.w;                     \
        float s_ = ((r[0] + r[1]) + (r[2] + r[3])) + ((r[4] + r[5]) + (r[6] + r[7])); \
        if (MAIN_LOW) {                                                             \
            s_ += __shfl_xor(s_, 8); s_ += __shfl_xor(s_, 16); s_ += __shfl_xor(s_, 32); \
        } else {                                                                    \
            s_ = dpp_add<0xB1>(s_); s_ = dpp_add<0x4E>(s_); s_ = dpp_add<0x141>(s_); \
        }                                                                           \
        int e_;                                                                     \
        (void)frexpf(s_, &e_);                                                      \
        eacc += e_;                                                                 \
        slogsum += SLOG;                                                            \
        int me_ = -e_;                                                              \
        _Pragma("unroll")                                                           \
        for (int m = 0; m < 8; ++m) ab[m] = ldexpf(r[m], me_);                      \
    }

// prefetch one app's operands: table block, emission chunk, slog
#define PREFETCH_APP(TB, E0, E1, SLOG, V1, V2, BLK, EB)                             \
    {                                                                               \
        const int4* tbase_ = Mtab4 + (V1) * 512 + (BLK);                            \
        _Pragma("unroll")                                                           \
        for (int i_ = 0; i_ < 8; ++i_) {                                            \
            int4 t_ = tbase_[i_];                                                   \
            TB[4 * i_ + 0] = t_.x; TB[4 * i_ + 1] = t_.y;                           \
            TB[4 * i_ + 2] = t_.z; TB[4 * i_ + 3] = t_.w;                           \
        }                                                                           \
        E0 = Em4[(V2) * 16 + (EB)];                                                 \
        E1 = Em4[(V2) * 16 + (EB) + 1];                                             \
        SLOG = gSlog[V1];                                                           \
    }

// ---------------- prep kernels ----------------
__global__ __launch_bounds__(256) void prep_emit(const float* __restrict__ log_emit) {
    int idx = blockIdx.x * 256 + threadIdx.x;  // 0..65535
    int v = idx >> 6;
    int j = idx & 63;
    gEmitT[idx] = expf(log_emit[(j + 1) * HMM_V + v]);
}

__global__ __launch_bounds__(64) void prep_small(const float* __restrict__ log_trans,
                                                 const float* __restrict__ log_pi) {
    int j = threadIdx.x;  // live state j+1
    for (int i = 0; i < 64; ++i)
        gET[i * 64 + j] = expf(log_trans[(i + 1) * HMM_S + (j + 1)]);
    float s = 0.f;
    for (int i = 0; i < HMM_S; ++i)
        s += expf(log_pi[i]) * expf(log_trans[i * HMM_S + (j + 1)]);
    gArow0[j] = s;
    float tc = log_trans[(j + 1) * HMM_S + 0];
    float mx = tc;
    for (int d = 1; d < 64; d <<= 1) mx = fmaxf(mx, __shfl_xor(mx, d));
    gTcs[j] = expf(tc - mx);
    if (j == 0) gTcmax = mx;
    for (int i = 0; i < 64; ++i)
        gP1[blk_idx(i, j)] = (__fp16)gET[i * 64 + j];
}

__global__ __launch_bounds__(64) void prep_table() {
    __shared__ float ETs[64 * 64];  // [i][j], broadcast reads
    __shared__ float ETp[64 * 66];  // [j][m], padded
    __shared__ float ev[64];
    const int m = threadIdx.x;
    const int v = blockIdx.x;
    for (int i = 0; i < 64; ++i) ETs[i * 64 + m] = gET[i * 64 + m];
    for (int j = 0; j < 64; ++j) ETp[j * 66 + m] = gET[j * 64 + m];
    ev[m] = gEmitT[v * 64 + m];
    __syncthreads();
    float acc[64];
#pragma unroll
    for (int i = 0; i < 64; ++i) acc[i] = 0.f;
    for (int j = 0; j < 64; ++j) {
        float w = ev[j] * ETp[j * 66 + m];
#pragma unroll
        for (int i = 0; i < 64; ++i) acc[i] = fmaf(ETs[i * 64 + j], w, acc[i]);
    }
    float mx = acc[0];
#pragma unroll
    for (int i = 1; i < 64; ++i) mx = fmaxf(mx, acc[i]);
    for (int d = 1; d < 64; d <<= 1) mx = fmaxf(mx, __shfl_xor(mx, d));
    int e;
    (void)frexpf(mx, &e);
    float sc = exp2f((float)(11 - e));
    if (m == 0) gSlog[v] = (float)(e - 11) * (float)LN2;
    __fp16* outp = gMtab + v * 4096;
    for (int i = 0; i < 64; ++i) outp[blk_idx(i, m)] = (__fp16)(acc[i] * sc);
}

// ---------------- main serial-scan kernel: 1 wave per batch ----------------
__global__ __launch_bounds__(64, 1) void hmm_fwd(const int* __restrict__ obvs,
                                                 float* __restrict__ out) {
    __shared__ __attribute__((aligned(16))) int obs_s[HMM_T + 16];
    __shared__ float a0lds[64];
    const int b = blockIdx.x;
    const int lane = threadIdx.x;
    const int h = lane >> 3, l = lane & 7;

    // stage obs into LDS with int4 loads (coalesced, 32 iters)
    {
        const int4* obs4 = (const int4*)(obvs + b * HMM_T);
        int4* lds4 = (int4*)obs_s;
        for (int k = lane; k < HMM_T / 4; k += 64) lds4[k] = obs4[k];
        if (lane < 16) obs_s[HMM_T + lane] = 0;  // pad for tail prefetch
    }

    const int blkE = (l * 8 + h) * 8;  // int4 offset, even apps
    const int blkO = (h * 8 + l) * 8;  // odd apps
    const int ebE = h * 2;             // float4 emission offset, even
    const int ebO = l * 2;             // odd

    const int4* Mtab4 = (const int4*)gMtab;     // 512 int4 per v
    const int4* P14 = (const int4*)gP1;
    const float4* Em4 = (const float4*)gEmitT;  // 16 float4 per v
    const int2* obs2 = (const int2*)obs_s;      // obs2[a] = (obs[2a], obs[2a+1])

    __syncthreads();

    // ---- init t=0 (exact: includes bookend state) ----
    int o0 = obs_s[0];
    float a0 = gArow0[lane] * gEmitT[o0 * 64 + lane];
    a0lds[lane] = a0;
    __syncthreads();
    float ab[8];
#pragma unroll
    for (int k = 0; k < 8; ++k) ab[k] = a0lds[l * 8 + k];  // ab[k] = alpha[8l+k]

    int eacc = 0;
    float slogsum = 0.f;

    // depth-4 ring: buffer p serves apps == p (mod 4); parity(buf) = p&1
    int tb0[32], tb1[32], tb2[32], tb3[32];
    float4 e00, e01, e10, e11, e20, e21, e30, e31;
    float sl0, sl1, sl2, sl3;
    int2 obp0, obp1, obp2, obp3;

    // ---- prologue: prefetch apps 0 (P1), 1, 2; prime obs-pair ring for 3..6 ----
    {
#pragma unroll
        for (int i = 0; i < 8; ++i) {
            int4 t = P14[blkE + i];
            tb0[4 * i + 0] = t.x; tb0[4 * i + 1] = t.y;
            tb0[4 * i + 2] = t.z; tb0[4 * i + 3] = t.w;
        }
        int v2 = obs_s[1];
        e00 = Em4[v2 * 16 + ebE];
        e01 = Em4[v2 * 16 + ebE + 1];
        sl0 = 0.f;
        int v1a = obs_s[2], v2a = obs_s[3];
        PREFETCH_APP(tb1, e10, e11, sl1, v1a, v2a, blkO, ebO)
        int v1b = obs_s[4], v2b = obs_s[5];
        PREFETCH_APP(tb2, e20, e21, sl2, v1b, v2b, blkE, ebE)
        obp3 = obs2[3];
        obp0 = obs2[4];
        obp1 = obs2[5];
        obp2 = obs2[6];
    }

    for (int g = 0; g < 1024; ++g) {
        const int a = 4 * g;
        // phase 0: compute app a (buf0, even); prefetch app a+3 (odd) into buf3
        PREFETCH_APP(tb3, e30, e31, sl3, obp3.x, obp3.y, blkO, ebO)
        obp3 = obs2[a + 7];
        COMPUTE_APP(tb0, e00, e01, sl0, true)
        // phase 1: compute app a+1 (buf1, odd); prefetch app a+4 (even) into buf0
        PREFETCH_APP(tb0, e00, e01, sl0, obp0.x, obp0.y, blkE, ebE)
        obp0 = obs2[a + 8];
        COMPUTE_APP(tb1, e10, e11, sl1, false)
        // phase 2: compute app a+2 (buf2, even); prefetch app a+5 (odd) into buf1
        PREFETCH_APP(tb1, e10, e11, sl1, obp1.x, obp1.y, blkO, ebO)
        obp1 = obs2[a + 9];
        COMPUTE_APP(tb2, e20, e21, sl2, true)
        // phase 3: compute app a+3 (buf3, odd); prefetch app a+6 (even) into buf2
        PREFETCH_APP(tb2, e20, e21, sl2, obp2.x, obp2.y, blkE, ebE)
        obp2 = obs2[a + 10];
        COMPUTE_APP(tb3, e30, e31, sl3, false)
    }

    // ---- termination: last app odd -> ab[m] = alpha[8l+m] ----
    float t = 0.f;
#pragma unroll
    for (int m = 0; m < 8; ++m) t += ab[m] * gTcs[l * 8 + m];
    t = dpp_add<0xB1>(t);
    t = dpp_add<0x4E>(t);
    t = dpp_add<0x141>(t);
    if (lane == 0)
        out[b] = (float)((double)slogsum + (double)eacc * LN2 + (double)gTcmax +
                         (double)__logf(t));
}

// ---------------- launch ----------------
extern "C" void kernel_launch(void* const* d_in, const int* in_sizes, int n_in,
                              void* d_out, int out_size, void* d_ws, size_t ws_size,
                              hipStream_t stream) {
    const float* log_trans = (const float*)d_in[0];  // 65*65
    const float* log_emit  = (const float*)d_in[1];  // 65*1024
    const float* log_pi    = (const float*)d_in[2];  // 65
    const int*   obvs      = (const int*)d_in[3];    // 128*8192
    float* out = (float*)d_out;

    prep_emit<<<256, 256, 0, stream>>>(log_emit);
    prep_small<<<1, 64, 0, stream>>>(log_trans, log_pi);
    prep_table<<<1024, 64, 0, stream>>>();
    hmm_fwd<<<HMM_B, 64, 0, stream>>>(obvs, out);
}